// Round 1
// baseline (6656.419 us; speedup 1.0000x reference)
//
#include <hip/hip_runtime.h>
#include <math.h>

#define D_MODEL   768
#define N_LAYER   4
#define D_STATE   128
#define D_CONV    4
#define HEADDIM   64
#define CHUNK     64
#define NCHUNK    32      // SEQLEN / CHUNK
#define VOCAB     50288
#define D_INNER   1536
#define NHEADS    24
#define CONV_DIM  1792    // D_INNER + 2*D_STATE
#define D_IN_PROJ 3352    // 2*D_INNER + 2*D_STATE + NHEADS
#define SEQLEN    2048
#define EPS       1e-5f

// ---------------- block-wide reduction (256 threads = 4 waves) ----------------
__device__ __forceinline__ float blk_reduce_sum(float v, float* red) {
  #pragma unroll
  for (int off = 32; off > 0; off >>= 1) v += __shfl_down(v, off, 64);
  if ((threadIdx.x & 63) == 0) red[threadIdx.x >> 6] = v;
  __syncthreads();
  float s = red[0] + red[1] + red[2] + red[3];
  __syncthreads();
  return s;
}

__device__ __forceinline__ float silu_f(float x) {
  return x / (1.f + expf(-x));
}

// ---------------- embedding gather ----------------
__global__ void embed_k(const int* __restrict__ ids, const float* __restrict__ emb,
                        float* __restrict__ x) {
  int t = blockIdx.x;
  size_t src = (size_t)ids[t] * D_MODEL;
  for (int i = threadIdx.x; i < D_MODEL; i += 256)
    x[(size_t)t * D_MODEL + i] = emb[src + i];
}

// ---------------- rmsnorm over 768 (pre-layer + final) ----------------
__global__ void rmsnorm768_k(const float* __restrict__ in, const float* __restrict__ w,
                             float* __restrict__ out) {
  __shared__ float red[4];
  int t = blockIdx.x;
  const float* row = in + (size_t)t * D_MODEL;
  int i0 = threadIdx.x, i1 = i0 + 256, i2 = i0 + 512;
  float v0 = row[i0], v1 = row[i1], v2 = row[i2];
  float ss = blk_reduce_sum(v0 * v0 + v1 * v1 + v2 * v2, red);
  float sc = rsqrtf(ss * (1.f / D_MODEL) + EPS);
  float* orow = out + (size_t)t * D_MODEL;
  orow[i0] = v0 * sc * w[i0];
  orow[i1] = v1 * sc * w[i1];
  orow[i2] = v2 * sc * w[i2];
}

// ---------------- gated rmsnorm over 1536: out = rms(y*silu(z)) * w ----------------
__global__ void gated_rmsnorm_k(const float* __restrict__ y, const float* __restrict__ zx,
                                const float* __restrict__ w, float* __restrict__ out) {
  __shared__ float red[4];
  int t = blockIdx.x;
  const float* yr = y + (size_t)t * D_INNER;
  const float* zr = zx + (size_t)t * D_IN_PROJ;   // z = first 1536 of zxbcdt
  float v[6];
  float ss = 0.f;
  #pragma unroll
  for (int i = 0; i < 6; i++) {
    int idx = threadIdx.x + i * 256;
    float val = yr[idx] * silu_f(zr[idx]);
    v[i] = val;
    ss += val * val;
  }
  ss = blk_reduce_sum(ss, red);
  float sc = rsqrtf(ss * (1.f / D_INNER) + EPS);
  float* orow = out + (size_t)t * D_INNER;
  #pragma unroll
  for (int i = 0; i < 6; i++) {
    int idx = threadIdx.x + i * 256;
    orow[idx] = v[i] * sc * w[idx];
  }
}

// ---------------- generic NT GEMM: C[M,N] = A[M,K] @ B[N,K]^T (+res) ----------------
// 64x64 tile, K-tile 32, 256 threads, each thread 4x4. M must be /64; N guarded.
#define GKT 32
__global__ __launch_bounds__(256) void gemm_nt_k(
    const float* __restrict__ A, const float* __restrict__ B,
    float* __restrict__ C, const float* __restrict__ res,
    int M, int N, int K) {
  __shared__ __align__(16) float As[GKT][72];
  __shared__ __align__(16) float Bs[GKT][72];
  int bm = blockIdx.y * 64, bn = blockIdx.x * 64;
  int tx = threadIdx.x & 15, ty = threadIdx.x >> 4;
  float acc[4][4] = {};
  for (int k0 = 0; k0 < K; k0 += GKT) {
    #pragma unroll
    for (int r = 0; r < 8; r++) {
      int idx = threadIdx.x + r * 256;   // 0..2047
      int mm = idx >> 5;                 // 0..63
      int kk = idx & 31;
      As[kk][mm] = A[(size_t)(bm + mm) * K + k0 + kk];
      int nn = bn + mm;
      Bs[kk][mm] = (nn < N) ? B[(size_t)nn * K + k0 + kk] : 0.f;
    }
    __syncthreads();
    #pragma unroll
    for (int k = 0; k < GKT; k++) {
      float4 av = *(const float4*)&As[k][ty * 4];
      float4 bv = *(const float4*)&Bs[k][tx * 4];
      float a[4] = {av.x, av.y, av.z, av.w};
      float b[4] = {bv.x, bv.y, bv.z, bv.w};
      #pragma unroll
      for (int i = 0; i < 4; i++)
        #pragma unroll
        for (int j = 0; j < 4; j++)
          acc[i][j] += a[i] * b[j];
    }
    __syncthreads();
  }
  #pragma unroll
  for (int i = 0; i < 4; i++) {
    int m = bm + ty * 4 + i;
    #pragma unroll
    for (int j = 0; j < 4; j++) {
      int n = bn + tx * 4 + j;
      if (n < N) {
        float v = acc[i][j];
        if (res) v += res[(size_t)m * N + n];
        C[(size_t)m * N + n] = v;
      }
    }
  }
}

// ---------------- depthwise causal conv4 + silu on xBC; softplus dt ----------------
__global__ void conv_dt_k(const float* __restrict__ zx, const float* __restrict__ cw,
                          const float* __restrict__ cb, const float* __restrict__ dtb,
                          float* __restrict__ xbc, float* __restrict__ dtbuf) {
  int idx = blockIdx.x * 256 + threadIdx.x;     // over SEQLEN*CONV_DIM
  int t = idx / CONV_DIM, ch = idx - t * CONV_DIM;
  float acc = cb[ch];
  #pragma unroll
  for (int k = 0; k < 4; k++) {
    int tt = t - 3 + k;
    if (tt >= 0) acc += cw[ch * 4 + k] * zx[(size_t)tt * D_IN_PROJ + D_INNER + ch];
  }
  xbc[(size_t)t * CONV_DIM + ch] = silu_f(acc);
  if (ch < NHEADS) {
    float raw = zx[(size_t)t * D_IN_PROJ + (D_INNER + CONV_DIM) + ch] + dtb[ch];
    dtbuf[t * NHEADS + ch] = (raw > 20.f) ? raw : log1pf(expf(raw));
  }
}

// ---------------- SSD phase 1: per (chunk, head): Y_diag + chunk states + Acum ----------------
__global__ __launch_bounds__(256) void ssd_phase1_k(
    const float* __restrict__ xbc, const float* __restrict__ dtbuf,
    const float* __restrict__ A_log, float* __restrict__ ybuf,
    float* __restrict__ states, float* __restrict__ acum_g) {
  __shared__ float Bs[64][129];
  __shared__ float Cs[64][129];
  __shared__ float Xs[64][65];
  __shared__ float Gs[64][65];
  __shared__ float ac[64], dts[64], decay[64];
  int c = blockIdx.x, h = blockIdx.y, tid = threadIdx.x;

  if (tid < 64) dts[tid] = dtbuf[(c * 64 + tid) * NHEADS + h];
  __syncthreads();
  if (tid == 0) {
    float Ah = -expf(A_log[h]);
    float s = 0.f;
    for (int l = 0; l < 64; l++) { s += Ah * dts[l]; ac[l] = s; }
  }
  __syncthreads();
  if (tid < 64) {
    decay[tid] = expf(ac[63] - ac[tid]);
    acum_g[(h * NCHUNK + c) * 64 + tid] = ac[tid];
  }
  for (int idx = tid; idx < 64 * 128; idx += 256) {
    int l = idx >> 7, n = idx & 127;
    const float* row = xbc + (size_t)(c * 64 + l) * CONV_DIM;
    Bs[l][n] = row[D_INNER + n];
    Cs[l][n] = row[D_INNER + D_STATE + n];
  }
  for (int idx = tid; idx < 64 * 64; idx += 256) {
    int l = idx >> 6, p = idx & 63;
    Xs[l][p] = xbc[(size_t)(c * 64 + l) * CONV_DIM + h * 64 + p] * dts[l];
  }
  __syncthreads();
  // states[p][n] = sum_l x[l][p]*decay[l]*B[l][n]
  for (int idx = tid; idx < 64 * 128; idx += 256) {
    int p = idx >> 7, n = idx & 127;
    float s = 0.f;
    for (int l = 0; l < 64; l++) s += Xs[l][p] * decay[l] * Bs[l][n];
    states[((size_t)(h * NCHUNK + c) * 64 + p) * 128 + n] = s;
  }
  // G[i][j] = (C_i . B_j) * exp(ac_i - ac_j), j<=i
  for (int idx = tid; idx < 64 * 64; idx += 256) {
    int i = idx >> 6, j = idx & 63;
    float g = 0.f;
    if (j <= i) {
      for (int n = 0; n < 128; n++) g += Cs[i][n] * Bs[j][n];
      g *= expf(ac[i] - ac[j]);
    }
    Gs[i][j] = g;
  }
  __syncthreads();
  // Y_diag[i][p] = sum_{j<=i} G[i][j]*X[j][p]
  for (int idx = tid; idx < 64 * 64; idx += 256) {
    int i = idx >> 6, p = idx & 63;
    float yv = 0.f;
    for (int j = 0; j <= i; j++) yv += Gs[i][j] * Xs[j][p];
    ybuf[(size_t)(c * 64 + i) * D_INNER + h * 64 + p] = yv;
  }
}

// ---------------- SSD phase 2: sequential inter-chunk state scan per head ----------------
__global__ void ssd_scan_k(const float* __restrict__ states, const float* __restrict__ acum_g,
                           float* __restrict__ sprefix) {
  int h = blockIdx.x, tid = threadIdx.x;
  float S[32];
  #pragma unroll
  for (int i = 0; i < 32; i++) S[i] = 0.f;
  for (int c = 0; c < NCHUNK; c++) {
    size_t base = (size_t)(h * NCHUNK + c) * 8192;
    float d = expf(acum_g[(h * NCHUNK + c) * 64 + 63]);
    #pragma unroll
    for (int i = 0; i < 32; i++) {
      size_t off = base + tid + i * 256;
      sprefix[off] = S[i];
      S[i] = d * S[i] + states[off];
    }
  }
}

// ---------------- SSD phase 3: Y += exp(Acum)*C.Sprefix + x*D ----------------
__global__ __launch_bounds__(256) void ssd_phase3_k(
    const float* __restrict__ xbc, const float* __restrict__ sprefix,
    const float* __restrict__ acum_g, const float* __restrict__ Dv,
    float* __restrict__ ybuf) {
  __shared__ float Sp[64][129];
  __shared__ float Cs[64][129];
  __shared__ float ac[64];
  int c = blockIdx.x, h = blockIdx.y, tid = threadIdx.x;
  if (tid < 64) ac[tid] = acum_g[(h * NCHUNK + c) * 64 + tid];
  for (int idx = tid; idx < 64 * 128; idx += 256) {
    int p = idx >> 7, n = idx & 127;
    Sp[p][n] = sprefix[((size_t)(h * NCHUNK + c) * 64 + p) * 128 + n];
    Cs[p][n] = xbc[(size_t)(c * 64 + p) * CONV_DIM + D_INNER + D_STATE + n];
  }
  __syncthreads();
  float Dh = Dv[h];
  for (int idx = tid; idx < 64 * 64; idx += 256) {
    int l = idx >> 6, p = idx & 63;
    float s = 0.f;
    for (int n = 0; n < 128; n++) s += Cs[l][n] * Sp[p][n];
    size_t yi = (size_t)(c * 64 + l) * D_INNER + h * 64 + p;
    float xv = xbc[(size_t)(c * 64 + l) * CONV_DIM + h * 64 + p];
    ybuf[yi] += expf(ac[l]) * s + xv * Dh;
  }
}

// ---------------- host launch ----------------
extern "C" void kernel_launch(void* const* d_in, const int* in_sizes, int n_in,
                              void* d_out, int out_size, void* d_ws, size_t ws_size,
                              hipStream_t stream) {
  const int*   ids  = (const int*)d_in[0];
  const float* emb  = (const float*)d_in[1];
  const float* ipw  = (const float*)d_in[2];   // (4, 3352, 768)
  const float* cw   = (const float*)d_in[3];   // (4, 1792, 4)
  const float* cb   = (const float*)d_in[4];   // (4, 1792)
  const float* dtb  = (const float*)d_in[5];   // (4, 24)
  const float* alog = (const float*)d_in[6];   // (4, 24)
  const float* Dv   = (const float*)d_in[7];   // (4, 24)
  const float* mnw  = (const float*)d_in[8];   // (4, 1536)
  const float* opw  = (const float*)d_in[9];   // (4, 768, 1536)
  const float* lnw  = (const float*)d_in[10];  // (4, 768)
  const float* nfw  = (const float*)d_in[11];  // (768,)
  float* out = (float*)d_out;

  // Scratch layout. Small persistent buffers (x, u) always in d_ws (12.6 MB).
  // Big per-layer transients (105.4 MB) go in d_ws if it fits, else in d_out
  // (412 MB; fully dead before the final vocab GEMM writes it).
  const size_t SMALL_F = 2ull * SEQLEN * D_MODEL;
  const size_t BIG_F = (size_t)SEQLEN * D_IN_PROJ + (size_t)SEQLEN * CONV_DIM +
                       (size_t)SEQLEN * NHEADS + (size_t)SEQLEN * D_INNER +
                       2ull * NHEADS * NCHUNK * CHUNK * D_STATE +
                       (size_t)NHEADS * NCHUNK * CHUNK;
  float* x = (float*)d_ws;
  float* u = x + (size_t)SEQLEN * D_MODEL;
  float* big = (ws_size >= (SMALL_F + BIG_F) * sizeof(float))
                   ? (u + (size_t)SEQLEN * D_MODEL)
                   : (float*)d_out;
  float* zx      = big;
  float* xbc     = zx + (size_t)SEQLEN * D_IN_PROJ;
  float* dtbuf   = xbc + (size_t)SEQLEN * CONV_DIM;
  float* ybuf    = dtbuf + (size_t)SEQLEN * NHEADS;
  float* states  = ybuf + (size_t)SEQLEN * D_INNER;
  float* sprefix = states + (size_t)NHEADS * NCHUNK * CHUNK * D_STATE;
  float* acum    = sprefix + (size_t)NHEADS * NCHUNK * CHUNK * D_STATE;

  embed_k<<<SEQLEN, 256, 0, stream>>>(ids, emb, x);

  for (int i = 0; i < N_LAYER; i++) {
    rmsnorm768_k<<<SEQLEN, 256, 0, stream>>>(x, lnw + i * D_MODEL, u);
    gemm_nt_k<<<dim3((D_IN_PROJ + 63) / 64, SEQLEN / 64), 256, 0, stream>>>(
        u, ipw + (size_t)i * D_IN_PROJ * D_MODEL, zx, nullptr, SEQLEN, D_IN_PROJ, D_MODEL);
    conv_dt_k<<<(SEQLEN * CONV_DIM) / 256, 256, 0, stream>>>(
        zx, cw + (size_t)i * CONV_DIM * D_CONV, cb + (size_t)i * CONV_DIM,
        dtb + i * NHEADS, xbc, dtbuf);
    ssd_phase1_k<<<dim3(NCHUNK, NHEADS), 256, 0, stream>>>(
        xbc, dtbuf, alog + i * NHEADS, ybuf, states, acum);
    ssd_scan_k<<<NHEADS, 256, 0, stream>>>(states, acum, sprefix);
    ssd_phase3_k<<<dim3(NCHUNK, NHEADS), 256, 0, stream>>>(
        xbc, sprefix, acum, Dv + i * NHEADS, ybuf);
    gated_rmsnorm_k<<<SEQLEN, 256, 0, stream>>>(ybuf, zx, mnw + i * D_INNER, xbc);
    gemm_nt_k<<<dim3(D_MODEL / 64, SEQLEN / 64), 256, 0, stream>>>(
        xbc, opw + (size_t)i * D_MODEL * D_INNER, x, x, SEQLEN, D_MODEL, D_INNER);
  }

  rmsnorm768_k<<<SEQLEN, 256, 0, stream>>>(x, nfw, u);
  gemm_nt_k<<<dim3((VOCAB + 63) / 64, SEQLEN / 64), 256, 0, stream>>>(
      u, emb, out, nullptr, SEQLEN, VOCAB, D_MODEL);
}